// Round 6
// baseline (125.321 us; speedup 1.0000x reference)
//
#include <hip/hip_runtime.h>

#define N_ROWS   32768
#define N_COLS   1000
#define NBINS    10
#define BLKS     2048
#define K2BLKS   128
#define C0_TOTAL 32768000.0f   // = 125 * 2^18, exact in f32

// bin(v) = #{k in 1..9 : v >= logit(k/10)}
__device__ __forceinline__ int bin_of(float v) {
    int b = 0;
    b += (v >= -2.19722458f);
    b += (v >= -1.38629436f);
    b += (v >= -0.84729786f);
    b += (v >= -0.40546511f);
    b += (v >=  0.0f);
    b += (v >=  0.40546511f);
    b += (v >=  0.84729786f);
    b += (v >=  1.38629436f);
    b += (v >=  2.19722458f);
    return b;
}

#define BFLY_F(v)  do { v += __shfl_xor(v, 32); v += __shfl_xor(v, 16); \
                        v += __shfl_xor(v, 8);  v += __shfl_xor(v, 4);  \
                        v += __shfl_xor(v, 2);  v += __shfl_xor(v, 1); } while (0)
#define BFLY16_F(v) do { v += __shfl_xor(v, 8); v += __shfl_xor(v, 4);  \
                         v += __shfl_xor(v, 2); v += __shfl_xor(v, 1); } while (0)
#define BFLY_U(v)  do { v += (unsigned)__shfl_xor((int)(v), 32); \
                        v += (unsigned)__shfl_xor((int)(v), 16); \
                        v += (unsigned)__shfl_xor((int)(v), 8);  \
                        v += (unsigned)__shfl_xor((int)(v), 4);  \
                        v += (unsigned)__shfl_xor((int)(v), 2);  \
                        v += (unsigned)__shfl_xor((int)(v), 1); } while (0)

// Fused kernel.
// Phase 1 (all 2048 blocks): 16 rows/block, one 16-lane group per row.
//   Per row: cumulative exp-sums T_k = sum_{x>=E_k} e^x (+xt) -> Trows[row*12..]
//   Per thread: cumulative counts C_k; lane-0-of-group fixes the target flip.
//   Block partials -> partialC (bin-major), then atomicAdd(ticket1).
// Phase 2 (last 128 FINISHERS only — already running, so spin is deadlock-free):
//   spin till ticket1==BLKS, reduce counts, build 10x10 weight table,
//   256 rows/virtual-block: loss = log(W[0]T0 + sum(W[b]-W[b-1])T_b
//                                       + e^{xt}(1-W[bxt])) - xt.
//   blockloss + ticket2; last ticket2 block writes the mean.
extern "C" __global__ __launch_bounds__(256)
void ghm_fused(const float* __restrict__ x, const int* __restrict__ target,
               unsigned int* __restrict__ ticket1, unsigned int* __restrict__ ticket2,
               unsigned int* __restrict__ partialC, float* __restrict__ Trows,
               float* __restrict__ blockloss, float* __restrict__ out) {
    __shared__ unsigned int cw[4][9];
    __shared__ int s_old;
    const int tid = threadIdx.x, wid = tid >> 6, lane = tid & 63;
    const int sub = lane & 15;
    const int bid = blockIdx.x;

    // ---------------- Phase 1 ----------------
    const int row = bid * 16 + (tid >> 4);          // 16 groups of 16 lanes
    const float* xrow = x + (size_t)row * N_COLS;

    int   t  = 0;
    float xt = 0.0f;
    if (sub == 0) t = target[row];                  // group leader only

    const float E1 = -2.19722458f, E2 = -1.38629436f, E3 = -0.84729786f,
                E4 = -0.40546511f, E5 = 0.0f,         E6 = 0.40546511f,
                E7 = 0.84729786f,  E8 = 1.38629436f,  E9 = 2.19722458f;

    unsigned int C1=0,C2=0,C3=0,C4=0,C5=0,C6=0,C7=0,C8=0,C9=0;
    float T0=0,T1=0,T2=0,T3=0,T4=0,T5=0,T6=0,T7=0,T8=0,T9=0;

    if (sub == 0) xt = xrow[t];                     // dependent load, hides under loop

#define ACC(c) do { const float e_ = __expf(c); T0 += e_; \
        T1 += ((c) >= E1) ? e_ : 0.f;  C1 += ((c) >= E1); \
        T2 += ((c) >= E2) ? e_ : 0.f;  C2 += ((c) >= E2); \
        T3 += ((c) >= E3) ? e_ : 0.f;  C3 += ((c) >= E3); \
        T4 += ((c) >= E4) ? e_ : 0.f;  C4 += ((c) >= E4); \
        T5 += ((c) >= E5) ? e_ : 0.f;  C5 += ((c) >= E5); \
        T6 += ((c) >= E6) ? e_ : 0.f;  C6 += ((c) >= E6); \
        T7 += ((c) >= E7) ? e_ : 0.f;  C7 += ((c) >= E7); \
        T8 += ((c) >= E8) ? e_ : 0.f;  C8 += ((c) >= E8); \
        T9 += ((c) >= E9) ? e_ : 0.f;  C9 += ((c) >= E9); } while (0)

#pragma unroll 5
    for (int k = 0; k < 15; ++k) {                  // f4 = k*16+sub <= 239 < 250
        const float4 v = reinterpret_cast<const float4*>(xrow)[k * 16 + sub];
        ACC(v.x); ACC(v.y); ACC(v.z); ACC(v.w);
    }
    if (sub < 10) {                                 // tail: f4 = 240..249
        const float4 v = reinterpret_cast<const float4*>(xrow)[240 + sub];
        ACC(v.x); ACC(v.y); ACC(v.z); ACC(v.w);
    }
#undef ACC

    // target element's g uses -x: swap its count from bin_of(xt) to bin_of(-xt)
    if (sub == 0) {
        const float nxt = -xt;
        C1 += (unsigned)(nxt >= E1) - (unsigned)(xt >= E1);
        C2 += (unsigned)(nxt >= E2) - (unsigned)(xt >= E2);
        C3 += (unsigned)(nxt >= E3) - (unsigned)(xt >= E3);
        C4 += (unsigned)(nxt >= E4) - (unsigned)(xt >= E4);
        C5 += (unsigned)(nxt >= E5) - (unsigned)(xt >= E5);
        C6 += (unsigned)(nxt >= E6) - (unsigned)(xt >= E6);
        C7 += (unsigned)(nxt >= E7) - (unsigned)(xt >= E7);
        C8 += (unsigned)(nxt >= E8) - (unsigned)(xt >= E8);
        C9 += (unsigned)(nxt >= E9) - (unsigned)(xt >= E9);
    }

    // 4-step butterfly within the 16-lane group: one shuffle op serves 4 rows
    BFLY16_F(T0); BFLY16_F(T1); BFLY16_F(T2); BFLY16_F(T3); BFLY16_F(T4);
    BFLY16_F(T5); BFLY16_F(T6); BFLY16_F(T7); BFLY16_F(T8); BFLY16_F(T9);
    if (sub == 0) {
        float4* dst = reinterpret_cast<float4*>(Trows + (size_t)row * 12);
        dst[0] = make_float4(T0, T1, T2, T3);
        dst[1] = make_float4(T4, T5, T6, T7);
        dst[2] = make_float4(T8, T9, xt, 0.f);
    }

    BFLY_U(C1); BFLY_U(C2); BFLY_U(C3); BFLY_U(C4); BFLY_U(C5);
    BFLY_U(C6); BFLY_U(C7); BFLY_U(C8); BFLY_U(C9);
    if (lane == 0) {
        cw[wid][0]=C1; cw[wid][1]=C2; cw[wid][2]=C3; cw[wid][3]=C4;
        cw[wid][4]=C5; cw[wid][5]=C6; cw[wid][6]=C7; cw[wid][7]=C8; cw[wid][8]=C9;
    }
    __syncthreads();
    if (tid < 9)
        partialC[tid * BLKS + bid] = cw[0][tid] + cw[1][tid] + cw[2][tid] + cw[3][tid];

    // ---------------- finisher election ----------------
    if (tid == 0) {
        __threadfence();                             // release partialC/Trows
        s_old = (int)atomicAdd(ticket1, 1u);
    }
    __syncthreads();
    const int old = s_old;
    if (old < BLKS - K2BLKS) return;                 // early finishers exit

    if (tid == 0) {                                  // spin among RUNNING blocks only
        long guard = 0;
        while (__hip_atomic_load(ticket1, __ATOMIC_ACQUIRE, __HIP_MEMORY_SCOPE_AGENT)
               < (unsigned)BLKS) {
            __builtin_amdgcn_s_sleep(16);
            if (++guard > 100000000L) break;         // hang insurance (never triggers)
        }
    }
    __syncthreads();

    // ---------------- Phase 2 (128 virtual blocks) ----------------
    __shared__ float Cl[11];
    __shared__ float cnt[NBINS];
    __shared__ float Wt[NBINS][NBINS];
    __shared__ float red[4];
    __shared__ int   lastFlag;
    const int bid2 = old - (BLKS - K2BLKS);          // 0..127

    for (int b = wid; b < 9; b += 4) {
        unsigned int s = 0;
        for (int k = lane; k < BLKS; k += 64) s += partialC[b * BLKS + k];
        BFLY_U(s);
        if (lane == 0) Cl[b + 1] = (float)s;
    }
    if (tid == 0) { Cl[0] = C0_TOTAL; Cl[10] = 0.0f; }
    __syncthreads();
    if (tid < NBINS) cnt[tid] = Cl[tid] - Cl[tid + 1];   // all < 2^24: exact
    __syncthreads();
    if (tid < NBINS * NBINS) {
        const int tau = tid / NBINS, b = tid % NBINS;
        Wt[tau][b] = fminf(cnt[b] / cnt[tau], 1.0f);
    }
    __syncthreads();

    const int row2 = bid2 * 256 + tid;                   // 128*256 = 32768
    const float4* Tp = reinterpret_cast<const float4*>(Trows + (size_t)row2 * 12);
    const float4 t0 = Tp[0];
    const float4 t1 = Tp[1];
    const float4 t2 = Tp[2];
    const float xt2 = t2.z;
    const int   bt  = bin_of(-xt2);
    const int   bxt = bin_of(xt2);
    const float* W  = Wt[bt];
    float d = W[0] * t0.x;
    d += (W[1] - W[0]) * t0.y;
    d += (W[2] - W[1]) * t0.z;
    d += (W[3] - W[2]) * t0.w;
    d += (W[4] - W[3]) * t1.x;
    d += (W[5] - W[4]) * t1.y;
    d += (W[6] - W[5]) * t1.z;
    d += (W[7] - W[6]) * t1.w;
    d += (W[8] - W[7]) * t2.x;
    d += (W[9] - W[8]) * t2.y;
    d += __expf(xt2) * (1.0f - W[bxt]);                  // target weight is exactly 1
    float loss = __logf(d) - xt2;

    BFLY_F(loss);
    if (lane == 0) red[wid] = loss;
    __syncthreads();
    if (tid == 0) {
        blockloss[bid2] = (red[0] + red[1]) + (red[2] + red[3]);
        __threadfence();
        lastFlag = (atomicAdd(ticket2, 1u) == K2BLKS - 1);
    }
    __syncthreads();
    if (lastFlag) {                                      // block-uniform
        __threadfence();
        float s = 0.0f;
        if (tid < K2BLKS)
            s = __hip_atomic_load(&blockloss[tid], __ATOMIC_RELAXED, __HIP_MEMORY_SCOPE_AGENT);
        BFLY_F(s);
        if (lane == 0) red[wid] = s;
        __syncthreads();
        if (tid == 0)
            out[0] = ((red[0] + red[1]) + (red[2] + red[3])) / (float)N_ROWS;
    }
}

extern "C" void kernel_launch(void* const* d_in, const int* in_sizes, int n_in,
                              void* d_out, int out_size, void* d_ws, size_t ws_size,
                              hipStream_t stream) {
    const float* x      = (const float*)d_in[0];
    const int*   target = (const int*)d_in[1];
    // ws layout:
    //   ticket1 @ 0, ticket2 @ 4           (zeroed by the 8-B fill below)
    //   blockloss @ 64   : 128*4 B
    //   partialC  @ 1024 : 9*2048*4 = 73728 B
    //   Trows     @ 74752: 32768*12*4 = 1572864 B
    unsigned int* ticket1   = (unsigned int*)d_ws;
    unsigned int* ticket2   = (unsigned int*)((char*)d_ws + 4);
    float*        blockloss = (float*)((char*)d_ws + 64);
    unsigned int* partialC  = (unsigned int*)((char*)d_ws + 1024);
    float*        Trows     = (float*)((char*)d_ws + 74752);

    hipMemsetAsync(d_ws, 0, 8, stream);   // tickets only
    hipLaunchKernelGGL(ghm_fused, dim3(BLKS), dim3(256), 0, stream,
                       x, target, ticket1, ticket2, partialC, Trows, blockloss,
                       (float*)d_out);
}

// Round 7
// 56.061 us; speedup vs baseline: 2.2354x; 2.2354x over previous
//
#include <hip/hip_runtime.h>

#define N_ROWS   32768
#define N_COLS   1000
#define NBINS    10
#define K1_BLKS  2048
#define K2_BLKS  128
#define C0_TOTAL 32768000.0f   // = 125 * 2^18, exact in f32

// bin(v) = #{k in 1..9 : v >= logit(k/10)}
__device__ __forceinline__ int bin_of(float v) {
    int b = 0;
    b += (v >= -2.19722458f);
    b += (v >= -1.38629436f);
    b += (v >= -0.84729786f);
    b += (v >= -0.40546511f);
    b += (v >=  0.0f);
    b += (v >=  0.40546511f);
    b += (v >=  0.84729786f);
    b += (v >=  1.38629436f);
    b += (v >=  2.19722458f);
    return b;
}

#define BFLY_F(v)  do { v += __shfl_xor(v, 32); v += __shfl_xor(v, 16); \
                        v += __shfl_xor(v, 8);  v += __shfl_xor(v, 4);  \
                        v += __shfl_xor(v, 2);  v += __shfl_xor(v, 1); } while (0)
#define BFLY16_F(v) do { v += __shfl_xor(v, 8); v += __shfl_xor(v, 4);  \
                         v += __shfl_xor(v, 2); v += __shfl_xor(v, 1); } while (0)
#define BFLY_U(v)  do { v += (unsigned)__shfl_xor((int)(v), 32); \
                        v += (unsigned)__shfl_xor((int)(v), 16); \
                        v += (unsigned)__shfl_xor((int)(v), 8);  \
                        v += (unsigned)__shfl_xor((int)(v), 4);  \
                        v += (unsigned)__shfl_xor((int)(v), 2);  \
                        v += (unsigned)__shfl_xor((int)(v), 1); } while (0)

// K1: 16 rows/block, one 16-lane group per row (4 rows in flight per wave).
// Per row: cumulative exp-sums T_k = sum_{x>=E_k} e^x (+xt) -> Trows[row*12..]
// Per thread: cumulative counts C_k (all 4 groups reduced together per wave);
// group-leader fixes the target-element flip. Block 0 zeroes K2's ticket.
// NO fences: the kernel boundary orders partialC/Trows for K2.
extern "C" __global__ __launch_bounds__(256)
void ghm_pass1(const float* __restrict__ x, const int* __restrict__ target,
               unsigned int* __restrict__ partialC, float* __restrict__ Trows,
               unsigned int* __restrict__ ticket) {
    __shared__ unsigned int cw[4][9];
    const int tid = threadIdx.x, wid = tid >> 6, lane = tid & 63;
    const int sub = tid & 15;
    const int bid = blockIdx.x;
    if (bid == 0 && tid == 0) *ticket = 0u;

    const int row = bid * 16 + (tid >> 4);
    const float* xrow = x + (size_t)row * N_COLS;

    const float E1 = -2.19722458f, E2 = -1.38629436f, E3 = -0.84729786f,
                E4 = -0.40546511f, E5 = 0.0f,         E6 = 0.40546511f,
                E7 = 0.84729786f,  E8 = 1.38629436f,  E9 = 2.19722458f;

    const int   t  = target[row];     // same addr across the 16-lane group: broadcast
    const float xt = xrow[t];         // dependent load; hides under the main loop

    unsigned int C1=0,C2=0,C3=0,C4=0,C5=0,C6=0,C7=0,C8=0,C9=0;
    float T0=0,T1=0,T2=0,T3=0,T4=0,T5=0,T6=0,T7=0,T8=0,T9=0;

#define ACC(c) do { const float e_ = __expf(c); T0 += e_; \
        T1 += ((c) >= E1) ? e_ : 0.f;  C1 += ((c) >= E1); \
        T2 += ((c) >= E2) ? e_ : 0.f;  C2 += ((c) >= E2); \
        T3 += ((c) >= E3) ? e_ : 0.f;  C3 += ((c) >= E3); \
        T4 += ((c) >= E4) ? e_ : 0.f;  C4 += ((c) >= E4); \
        T5 += ((c) >= E5) ? e_ : 0.f;  C5 += ((c) >= E5); \
        T6 += ((c) >= E6) ? e_ : 0.f;  C6 += ((c) >= E6); \
        T7 += ((c) >= E7) ? e_ : 0.f;  C7 += ((c) >= E7); \
        T8 += ((c) >= E8) ? e_ : 0.f;  C8 += ((c) >= E8); \
        T9 += ((c) >= E9) ? e_ : 0.f;  C9 += ((c) >= E9); } while (0)

#pragma unroll 5
    for (int k = 0; k < 15; ++k) {                  // f4 = k*16+sub <= 239 < 250
        const float4 v = reinterpret_cast<const float4*>(xrow)[k * 16 + sub];
        ACC(v.x); ACC(v.y); ACC(v.z); ACC(v.w);
    }
    if (sub < 10) {                                 // tail: f4 = 240..249
        const float4 v = reinterpret_cast<const float4*>(xrow)[240 + sub];
        ACC(v.x); ACC(v.y); ACC(v.z); ACC(v.w);
    }
#undef ACC

    // target element's g uses -x: swap its count from bin_of(xt) to bin_of(-xt)
    if (sub == 0) {
        const float nxt = -xt;
        C1 += (unsigned)(nxt >= E1) - (unsigned)(xt >= E1);  // modular, exact overall
        C2 += (unsigned)(nxt >= E2) - (unsigned)(xt >= E2);
        C3 += (unsigned)(nxt >= E3) - (unsigned)(xt >= E3);
        C4 += (unsigned)(nxt >= E4) - (unsigned)(xt >= E4);
        C5 += (unsigned)(nxt >= E5) - (unsigned)(xt >= E5);
        C6 += (unsigned)(nxt >= E6) - (unsigned)(xt >= E6);
        C7 += (unsigned)(nxt >= E7) - (unsigned)(xt >= E7);
        C8 += (unsigned)(nxt >= E8) - (unsigned)(xt >= E8);
        C9 += (unsigned)(nxt >= E9) - (unsigned)(xt >= E9);
    }

    // 4-step butterfly within each 16-lane group (4 rows reduced concurrently)
    BFLY16_F(T0); BFLY16_F(T1); BFLY16_F(T2); BFLY16_F(T3); BFLY16_F(T4);
    BFLY16_F(T5); BFLY16_F(T6); BFLY16_F(T7); BFLY16_F(T8); BFLY16_F(T9);
    if (sub == 0) {
        float4* dst = reinterpret_cast<float4*>(Trows + (size_t)row * 12);
        dst[0] = make_float4(T0, T1, T2, T3);
        dst[1] = make_float4(T4, T5, T6, T7);
        dst[2] = make_float4(T8, T9, xt, 0.f);
    }

    // counts: full-wave butterfly folds all 4 groups at once (additive)
    BFLY_U(C1); BFLY_U(C2); BFLY_U(C3); BFLY_U(C4); BFLY_U(C5);
    BFLY_U(C6); BFLY_U(C7); BFLY_U(C8); BFLY_U(C9);
    if (lane == 0) {
        cw[wid][0]=C1; cw[wid][1]=C2; cw[wid][2]=C3; cw[wid][3]=C4;
        cw[wid][4]=C5; cw[wid][5]=C6; cw[wid][6]=C7; cw[wid][7]=C8; cw[wid][8]=C9;
    }
    __syncthreads();
    if (tid < 9)   // bin-major for coalesced K2 reads
        partialC[tid * K1_BLKS + bid] = cw[0][tid] + cw[1][tid] + cw[2][tid] + cw[3][tid];
}

// K2 (unchanged from round 5, proven): counts -> 10x10 weight table, per-row
// denom via Abel summation, last-block ticket folds the mean.
extern "C" __global__ __launch_bounds__(256)
void ghm_pass2(const unsigned int* __restrict__ partialC, const float* __restrict__ Trows,
               float* __restrict__ blockloss, unsigned int* __restrict__ ticket,
               float* __restrict__ out) {
    __shared__ float Cl[11];
    __shared__ float cnt[NBINS];
    __shared__ float Wt[NBINS][NBINS];
    __shared__ float red[4];
    __shared__ int   lastFlag;
    const int tid = threadIdx.x, wid = tid >> 6, lane = tid & 63;
    const int bid = blockIdx.x;

    for (int b = wid; b < 9; b += 4) {
        unsigned int s = 0;
        for (int k = lane; k < K1_BLKS; k += 64) s += partialC[b * K1_BLKS + k];
        BFLY_U(s);
        if (lane == 0) Cl[b + 1] = (float)s;
    }
    if (tid == 0) { Cl[0] = C0_TOTAL; Cl[10] = 0.0f; }
    __syncthreads();
    if (tid < NBINS) cnt[tid] = Cl[tid] - Cl[tid + 1];   // all < 2^24: exact
    __syncthreads();
    if (tid < NBINS * NBINS) {
        const int tau = tid / NBINS, b = tid % NBINS;
        Wt[tau][b] = fminf(cnt[b] / cnt[tau], 1.0f);     // cnt[tau] >= 1 always
    }
    __syncthreads();

    const int row = bid * 256 + tid;                     // 128*256 = 32768 exactly
    const float4* Tp = reinterpret_cast<const float4*>(Trows + (size_t)row * 12);
    const float4 t0 = Tp[0];
    const float4 t1 = Tp[1];
    const float4 t2 = Tp[2];
    const float xt  = t2.z;
    const int   bt  = bin_of(-xt);                       // target g-bin
    const int   bxt = bin_of(xt);                        // target's natural x-bin
    const float* W  = Wt[bt];
    float d = W[0] * t0.x;
    d += (W[1] - W[0]) * t0.y;
    d += (W[2] - W[1]) * t0.z;
    d += (W[3] - W[2]) * t0.w;
    d += (W[4] - W[3]) * t1.x;
    d += (W[5] - W[4]) * t1.y;
    d += (W[6] - W[5]) * t1.z;
    d += (W[7] - W[6]) * t1.w;
    d += (W[8] - W[7]) * t2.x;
    d += (W[9] - W[8]) * t2.y;
    d += __expf(xt) * (1.0f - W[bxt]);                   // target weight is exactly 1
    float loss = __logf(d) - xt;

    BFLY_F(loss);
    if (lane == 0) red[wid] = loss;
    __syncthreads();
    if (tid == 0) {
        blockloss[bid] = (red[0] + red[1]) + (red[2] + red[3]);
        __threadfence();
        lastFlag = (atomicAdd(ticket, 1u) == K2_BLKS - 1);
    }
    __syncthreads();
    if (lastFlag) {                                      // block-uniform
        __threadfence();
        float s = 0.0f;
        if (tid < K2_BLKS)
            s = __hip_atomic_load(&blockloss[tid], __ATOMIC_RELAXED, __HIP_MEMORY_SCOPE_AGENT);
        BFLY_F(s);
        if (lane == 0) red[wid] = s;
        __syncthreads();
        if (tid == 0)
            out[0] = ((red[0] + red[1]) + (red[2] + red[3])) / (float)N_ROWS;
    }
}

extern "C" void kernel_launch(void* const* d_in, const int* in_sizes, int n_in,
                              void* d_out, int out_size, void* d_ws, size_t ws_size,
                              hipStream_t stream) {
    const float* x      = (const float*)d_in[0];
    const int*   target = (const int*)d_in[1];
    // ws layout (all regions fully overwritten before read each call):
    //   partialC @ 0       : 9*2048*4  = 73728 B
    //   ticket   @ 81920   : 4 B       (zeroed by K1 block 0)
    //   blockloss@ 82048   : 128*4 B
    //   Trows    @ 98304   : 32768*12*4 = 1572864 B
    unsigned int* partialC  = (unsigned int*)d_ws;
    unsigned int* ticket    = (unsigned int*)((char*)d_ws + 81920);
    float*        blockloss = (float*)((char*)d_ws + 82048);
    float*        Trows     = (float*)((char*)d_ws + 98304);

    hipLaunchKernelGGL(ghm_pass1, dim3(K1_BLKS), dim3(256), 0, stream,
                       x, target, partialC, Trows, ticket);
    hipLaunchKernelGGL(ghm_pass2, dim3(K2_BLKS), dim3(256), 0, stream,
                       partialC, Trows, blockloss, ticket, (float*)d_out);
}